// Round 3
// baseline (399.408 us; speedup 1.0000x reference)
//
#include <hip/hip_runtime.h>
#include <math.h>

// Problem constants (match reference)
constexpr int N_ROWS = 100000;   // outputSize
constexpr int D      = 128;      // feature dim
constexpr int B      = 128;      // batch
constexpr int KP1    = 4097;     // K+1
constexpr int TOTAL_PAIRS = B * KP1;            // 524,416
constexpr float INV_T = 1.0f / 0.07f;
constexpr int N4 = N_ROWS * (D / 4);            // float4 per bank: 3.2M

constexpr int SCB = 2048;        // score blocks
constexpr int CPB = 1024;        // copy blocks
constexpr int SC_THREADS = SCB * 256;           // 524,288

// ---------------------------------------------------------------------------
__global__ void init_ws_kernel(float* ws) {
    if (threadIdx.x < 2) ws[threadIdx.x] = 0.0f;
}

__device__ __forceinline__ float dot4(float4 a, float4 b) {
    return a.x * b.x + a.y * b.y + a.z * b.z + a.w * b.w;
}

// ---------------------------------------------------------------------------
// Role by blockIdx%3: 1/3 of blocks copy (interleaved for overlap), 2/3 score.
// Score: ONE PAIR PER LANE. Each lane owns pair p, loops 32 float4 chunks of
// the two gathered rows (64 scattered lines per load instruction -> high MLP),
// accumulates both dots in registers. No per-pair shuffles; exp + coalesced
// store per lane; one butterfly per wave for the Z partial sums.
__global__ __launch_bounds__(256, 4) void mega_kernel(
    const float* __restrict__ v1, const float* __restrict__ v2,
    const int* __restrict__ idx,
    const float* __restrict__ mem1, const float* __restrict__ mem2,
    float* __restrict__ out,          // [0:T) unnorm out_v1, [T:2T) unnorm out_v2
    float* __restrict__ sums,         // ws: 2 floats
    float4* __restrict__ o1, float4* __restrict__ o2)
{
    const unsigned bx = blockIdx.x;
    const unsigned role = bx % 3u;

    if (role == 0u) {
        // ---- copy third ----
        int cid = bx / 3u;                            // 0..CPB-1
        const float4* __restrict__ m1 = (const float4*)mem1;
        const float4* __restrict__ m2 = (const float4*)mem2;
        int tid = cid * 256 + threadIdx.x;
        int stride = CPB * 256;
        for (int i = tid; i < N4; i += stride) {
            o1[i] = m1[i];
            o2[i] = m2[i];
        }
        return;
    }

    // ---- score two-thirds ----
    const int sid = (bx / 3u) * 2 + (role - 1);       // 0..SCB-1
    const int tid = sid * 256 + threadIdx.x;          // 0..524287

    const float4* __restrict__ m1 = (const float4*)mem1;
    const float4* __restrict__ m2 = (const float4*)mem2;
    const float4* __restrict__ vv1 = (const float4*)v1;
    const float4* __restrict__ vv2 = (const float4*)v2;

    float acc1 = 0.0f, acc2 = 0.0f;

    for (int p = tid; p < TOTAL_PAIRS; p += SC_THREADS) {
        int b = (int)((unsigned)p / (unsigned)KP1);   // magic-mul
        int row = idx[p];
        const float4* __restrict__ w1 = m1 + (size_t)row * 32;
        const float4* __restrict__ w2 = m2 + (size_t)row * 32;
        const float4* __restrict__ a1 = vv1 + b * 32;
        const float4* __restrict__ a2 = vv2 + b * 32;

        float d1 = 0.0f, d2 = 0.0f;
        #pragma unroll 8
        for (int c = 0; c < 32; ++c) {
            float4 x1 = w1[c];
            float4 x2 = w2[c];
            float4 y1 = a1[c];   // wave-uniform, L1-hit broadcast
            float4 y2 = a2[c];
            d1 += dot4(x2, y1);  // out_v1 = mem2 . v1
            d2 += dot4(x1, y2);  // out_v2 = mem1 . v2
        }

        float e1 = __expf(d1 * INV_T);
        float e2 = __expf(d2 * INV_T);
        out[p]               = e1;   // coalesced across the wave
        out[TOTAL_PAIRS + p] = e2;
        acc1 += e1;
        acc2 += e2;
    }

    // wave butterfly (64 lanes), then block, then one atomic per block
    #pragma unroll
    for (int off = 32; off >= 1; off >>= 1) {
        acc1 += __shfl_xor(acc1, off);
        acc2 += __shfl_xor(acc2, off);
    }
    __shared__ float s1[4], s2[4];
    const int wave = threadIdx.x >> 6;
    if ((threadIdx.x & 63) == 0) { s1[wave] = acc1; s2[wave] = acc2; }
    __syncthreads();
    if (threadIdx.x == 0) {
        float t1 = s1[0] + s1[1] + s1[2] + s1[3];
        float t2 = s2[0] + s2[1] + s2[2] + s2[3];
        atomicAdd(&sums[0], t1);
        atomicAdd(&sums[1], t2);
    }
}

// ---------------------------------------------------------------------------
// Scale scores by 1/Z and overwrite the y-rows of the copied banks with
// normalize(0.5*mem + 0.5*v). Runs after mega_kernel (stream-ordered).
__global__ __launch_bounds__(256) void finish_kernel(
    float* __restrict__ out, const float* __restrict__ sums,
    const float* __restrict__ v1, const float* __restrict__ v2,
    const int* __restrict__ y,
    const float* __restrict__ mem1, const float* __restrict__ mem2,
    float* __restrict__ o1, float* __restrict__ o2)
{
    // row updates: blocks 0..255, wave 0 of each
    if (blockIdx.x < 2 * B && threadIdx.x < 64) {
        int b    = blockIdx.x & (B - 1);
        int bank = blockIdx.x >> 7;
        int lane = threadIdx.x;
        const float2* __restrict__ m = (const float2*)(bank ? mem2 : mem1);
        const float2* __restrict__ v = (const float2*)(bank ? v2 : v1);
        float2* __restrict__ o       = (float2*)(bank ? o2 : o1);
        int row = y[b];
        float2 mv = m[(size_t)row * 64 + lane];
        float2 vv = v[b * 64 + lane];
        float2 u;
        u.x = 0.5f * mv.x + 0.5f * vv.x;
        u.y = 0.5f * mv.y + 0.5f * vv.y;
        float ss = u.x * u.x + u.y * u.y;
        #pragma unroll
        for (int off = 32; off >= 1; off >>= 1) ss += __shfl_xor(ss, off);
        float inv = 1.0f / sqrtf(ss);
        float2 r; r.x = u.x * inv; r.y = u.y * inv;
        o[(size_t)row * 64 + lane] = r;
    }

    // scale: grid-stride over both score regions
    float sc1 = (float)((double)TOTAL_PAIRS / ((double)sums[0] * (double)N_ROWS));
    float sc2 = (float)((double)TOTAL_PAIRS / ((double)sums[1] * (double)N_ROWS));
    int stride = gridDim.x * blockDim.x;
    for (int i = blockIdx.x * blockDim.x + threadIdx.x; i < 2 * TOTAL_PAIRS;
         i += stride) {
        out[i] *= (i < TOTAL_PAIRS) ? sc1 : sc2;
    }
}

// ---------------------------------------------------------------------------
extern "C" void kernel_launch(void* const* d_in, const int* in_sizes, int n_in,
                              void* d_out, int out_size, void* d_ws, size_t ws_size,
                              hipStream_t stream) {
    const float* v1   = (const float*)d_in[0];
    const float* v2   = (const float*)d_in[1];
    const int*   idx  = (const int*)d_in[2];
    const int*   y    = (const int*)d_in[3];
    const float* mem1 = (const float*)d_in[4];
    const float* mem2 = (const float*)d_in[5];

    float* out = (float*)d_out;
    float* out_mem1 = out + 2 * (size_t)TOTAL_PAIRS;
    float* out_mem2 = out_mem1 + (size_t)N_ROWS * D;
    float* sums = (float*)d_ws;

    init_ws_kernel<<<1, 64, 0, stream>>>(sums);

    mega_kernel<<<SCB + CPB, 256, 0, stream>>>(
        v1, v2, idx, mem1, mem2, out, sums,
        (float4*)out_mem1, (float4*)out_mem2);

    finish_kernel<<<1024, 256, 0, stream>>>(
        out, sums, v1, v2, y, mem1, mem2, out_mem1, out_mem2);
}

// Round 4
// 318.332 us; speedup vs baseline: 1.2547x; 1.2547x over previous
//
#include <hip/hip_runtime.h>
#include <math.h>

// Problem constants (match reference)
constexpr int N_ROWS = 100000;   // outputSize
constexpr int D      = 128;      // feature dim
constexpr int B      = 128;      // batch
constexpr int KP1    = 4097;     // K+1
constexpr int TOTAL_PAIRS = B * KP1;            // 524,416
constexpr float INV_T = 1.0f / 0.07f;
constexpr int N4 = N_ROWS * (D / 4);            // float4 per bank: 3.2M

typedef __attribute__((ext_vector_type(8))) short short8;  // 8 bf16 = 4 VGPRs
typedef __attribute__((ext_vector_type(4))) float f32x4;

// ---------------------------------------------------------------------------
__device__ __forceinline__ unsigned short f2bf(float f) {
    union { float f; unsigned u; } x; x.f = f;
    unsigned r = x.u + 0x7fffu + ((x.u >> 16) & 1u);   // RNE
    return (unsigned short)(r >> 16);
}
__device__ __forceinline__ float bf2f(unsigned short h) {
    union { unsigned u; float f; } x; x.u = ((unsigned)h) << 16;
    return x.f;
}
__device__ __forceinline__ short8 cvt8(float4 a, float4 b) {
    short8 r;
    r[0] = (short)f2bf(a.x); r[1] = (short)f2bf(a.y);
    r[2] = (short)f2bf(a.z); r[3] = (short)f2bf(a.w);
    r[4] = (short)f2bf(b.x); r[5] = (short)f2bf(b.y);
    r[6] = (short)f2bf(b.z); r[7] = (short)f2bf(b.w);
    return r;
}

// ---------------------------------------------------------------------------
// Convert v1,v2 (128x128 f32 each) to bf16 stash (at front of d_out) + zero sums.
__global__ __launch_bounds__(256) void init_kernel(
    const float* __restrict__ v1, const float* __restrict__ v2,
    unsigned short* __restrict__ vbf,   // [2][128][128] bf16
    float* __restrict__ sums)
{
    int tid = blockIdx.x * 256 + threadIdx.x;    // 64 blocks -> 16384 threads
    vbf[tid]         = f2bf(v1[tid]);
    vbf[16384 + tid] = f2bf(v2[tid]);
    if (tid < 2) sums[tid] = 0.0f;
}

// ---------------------------------------------------------------------------
// Dense GEMM: S1[m][n] = sum_k mem2[m][k]*v1[n][k], S2 = mem1 . v2  (bf16 MFMA).
// Packed store {bf16 s1, bf16 s2} per (m,n) into SS (= out_mem1 region, scratch).
// Fused streaming copy mem2 -> out_mem2 (rows are L2-hot from the A-frag loads).
// No LDS; wave = 16 rows x 128 cols; WG (4 waves) = 64 rows.
__global__ __launch_bounds__(256) void gemm_kernel(
    const float* __restrict__ mem1, const float* __restrict__ mem2,
    const unsigned short* __restrict__ vbf,   // [2][128][128] bf16
    unsigned* __restrict__ SS,                // [N_ROWS][128] packed scores
    const float4* __restrict__ m2_4, float4* __restrict__ o2_4)
{
    const int wg   = blockIdx.x;
    const int wave = threadIdx.x >> 6;
    const int lane = threadIdx.x & 63;
    const int quad = lane >> 4;
    const int lr   = lane & 15;
    const int m0   = wg * 64 + wave * 16;

    // A fragments: lane holds A[m = m0+lr][k = s*32 + quad*8 + j], j=0..7
    int am = m0 + lr; if (am > N_ROWS - 1) am = N_ROWS - 1;
    const float4* r1 = (const float4*)(mem1 + (size_t)am * 128);
    const float4* r2 = (const float4*)(mem2 + (size_t)am * 128);
    short8 a1[4], a2[4];
    #pragma unroll
    for (int s = 0; s < 4; ++s) {
        int c4 = s * 8 + quad * 2;          // float4 index of k = s*32+quad*8
        a1[s] = cvt8(r1[c4], r1[c4 + 1]);
        a2[s] = cvt8(r2[c4], r2[c4 + 1]);
    }

    // B fragments from bf16 V stash: B^T row-major, lane holds
    // v[n = n0+lr][k = s*32 + quad*8 + j]  (16B aligned short8 loads, L2-hot)
    const short8* vb = (const short8*)vbf;   // index in units of 8 bf16

    #pragma unroll
    for (int ct = 0; ct < 8; ++ct) {
        const int n0 = ct * 16;
        f32x4 acc1 = {0.f, 0.f, 0.f, 0.f};
        f32x4 acc2 = {0.f, 0.f, 0.f, 0.f};
        #pragma unroll
        for (int s = 0; s < 4; ++s) {
            short8 b1 = vb[(n0 + lr) * 16 + s * 4 + quad];          // v1
            short8 b2 = vb[2048 + (n0 + lr) * 16 + s * 4 + quad];   // v2
            acc1 = __builtin_amdgcn_mfma_f32_16x16x32_bf16(a2[s], b1, acc1, 0, 0, 0);
            acc2 = __builtin_amdgcn_mfma_f32_16x16x32_bf16(a1[s], b2, acc2, 0, 0, 0);
        }
        // C/D layout: col = lane&15, row = quad*4 + reg
        #pragma unroll
        for (int r = 0; r < 4; ++r) {
            int m = m0 + quad * 4 + r;
            if (m < N_ROWS) {
                unsigned pk = (unsigned)f2bf(acc1[r]) |
                              ((unsigned)f2bf(acc2[r]) << 16);
                SS[(size_t)m * 128 + n0 + lr] = pk;   // 64B contig per quad
            }
        }
    }

    // fused copy: this WG's 64-row window of mem2 -> out_mem2
    const int base4 = wg * 2048;              // 64 rows * 32 float4
    #pragma unroll
    for (int j = 0; j < 8; ++j) {
        int i = base4 + j * 256 + threadIdx.x;
        if (i < N4) o2_4[i] = m2_4[i];
    }
}

// ---------------------------------------------------------------------------
// Gather: one pair per thread, single packed 4B read from SS, exp, store,
// global sum for Z.
__global__ __launch_bounds__(256) void gather_kernel(
    const int* __restrict__ idx, const unsigned* __restrict__ SS,
    float* __restrict__ out, float* __restrict__ sums)
{
    int p = blockIdx.x * 256 + threadIdx.x;
    float e1 = 0.0f, e2 = 0.0f;
    if (p < TOTAL_PAIRS) {
        int b   = (int)((unsigned)p / (unsigned)KP1);
        int row = idx[p];
        unsigned pk = SS[(size_t)row * 128 + b];
        e1 = __expf(bf2f((unsigned short)(pk & 0xffffu)) * INV_T);
        e2 = __expf(bf2f((unsigned short)(pk >> 16)) * INV_T);
        out[p]               = e1;
        out[TOTAL_PAIRS + p] = e2;
    }
    #pragma unroll
    for (int off = 32; off >= 1; off >>= 1) {
        e1 += __shfl_xor(e1, off);
        e2 += __shfl_xor(e2, off);
    }
    __shared__ float s1[4], s2[4];
    const int wave = threadIdx.x >> 6;
    if ((threadIdx.x & 63) == 0) { s1[wave] = e1; s2[wave] = e2; }
    __syncthreads();
    if (threadIdx.x == 0) {
        atomicAdd(&sums[0], s1[0] + s1[1] + s1[2] + s1[3]);
        atomicAdd(&sums[1], s2[0] + s2[1] + s2[2] + s2[3]);
    }
}

// ---------------------------------------------------------------------------
// After gather consumed SS: copy mem1 -> out_mem1, and scale scores by 1/Z.
__global__ __launch_bounds__(256) void copy_scale_kernel(
    const float4* __restrict__ m1_4, float4* __restrict__ o1_4,
    float* __restrict__ out, const float* __restrict__ sums)
{
    const int stride = gridDim.x * 256;
    const int t = blockIdx.x * 256 + threadIdx.x;
    for (int i = t; i < N4; i += stride) o1_4[i] = m1_4[i];

    float sc1 = (float)((double)TOTAL_PAIRS / ((double)sums[0] * (double)N_ROWS));
    float sc2 = (float)((double)TOTAL_PAIRS / ((double)sums[1] * (double)N_ROWS));
    for (int i = t; i < 2 * TOTAL_PAIRS; i += stride)
        out[i] *= (i < TOTAL_PAIRS) ? sc1 : sc2;
}

// ---------------------------------------------------------------------------
// y-row updates (must run after both copies): o[y[b]] = normalize(.5*mem+.5*v)
__global__ __launch_bounds__(64) void update_rows_kernel(
    const float* __restrict__ v1, const float* __restrict__ v2,
    const int* __restrict__ y,
    const float* __restrict__ mem1, const float* __restrict__ mem2,
    float* __restrict__ o1, float* __restrict__ o2)
{
    int b    = blockIdx.x & (B - 1);
    int bank = blockIdx.x >> 7;
    int lane = threadIdx.x;
    const float2* __restrict__ m = (const float2*)(bank ? mem2 : mem1);
    const float2* __restrict__ v = (const float2*)(bank ? v2 : v1);
    float2* __restrict__ o       = (float2*)(bank ? o2 : o1);
    int row = y[b];
    float2 mv = m[(size_t)row * 64 + lane];
    float2 vv = v[b * 64 + lane];
    float2 u;
    u.x = 0.5f * mv.x + 0.5f * vv.x;
    u.y = 0.5f * mv.y + 0.5f * vv.y;
    float ss = u.x * u.x + u.y * u.y;
    #pragma unroll
    for (int off = 32; off >= 1; off >>= 1) ss += __shfl_xor(ss, off);
    float inv = 1.0f / sqrtf(ss);
    float2 r; r.x = u.x * inv; r.y = u.y * inv;
    o[(size_t)row * 64 + lane] = r;
}

// ---------------------------------------------------------------------------
extern "C" void kernel_launch(void* const* d_in, const int* in_sizes, int n_in,
                              void* d_out, int out_size, void* d_ws, size_t ws_size,
                              hipStream_t stream) {
    const float* v1   = (const float*)d_in[0];
    const float* v2   = (const float*)d_in[1];
    const int*   idx  = (const int*)d_in[2];
    const int*   y    = (const int*)d_in[3];
    const float* mem1 = (const float*)d_in[4];
    const float* mem2 = (const float*)d_in[5];

    float* out      = (float*)d_out;
    float* out_mem1 = out + 2 * (size_t)TOTAL_PAIRS;
    float* out_mem2 = out_mem1 + (size_t)N_ROWS * D;
    float* sums     = (float*)d_ws;

    // bf16 V stash lives in the (not-yet-written) out_v1 region; SS (packed
    // bf16 score pairs) lives in the out_mem1 region until copy_scale.
    unsigned short* vbf = (unsigned short*)d_out;
    unsigned*       SS  = (unsigned*)out_mem1;

    init_kernel<<<64, 256, 0, stream>>>(v1, v2, vbf, sums);

    gemm_kernel<<<(N_ROWS + 63) / 64, 256, 0, stream>>>(
        mem1, mem2, vbf, SS, (const float4*)mem2, (float4*)out_mem2);

    gather_kernel<<<(TOTAL_PAIRS + 255) / 256, 256, 0, stream>>>(
        idx, SS, out, sums);

    copy_scale_kernel<<<2048, 256, 0, stream>>>(
        (const float4*)mem1, (float4*)out_mem1, out, sums);

    update_rows_kernel<<<2 * B, 64, 0, stream>>>(
        v1, v2, y, mem1, mem2, out_mem1, out_mem2);
}